// Round 5
// baseline (40.658 us; speedup 1.0000x reference)
//
#include <hip/hip_runtime.h>
#include <hip/hip_bf16.h>
#include <math.h>

// Problem constants (DeepFM)
#define BTOT   16384
#define NF     26
#define VOCAB  100000
#define EDIM   16
#define DD     13
#define KPAD   448      // 429 padded to 14*32
#define KREAL  429
#define N1     256
#define N2     128
#define SPB    64       // samples per block
#define APAD   456      // A tile row stride (448+8)
#define H2PAD  264      // H2 tile row stride (256+8)

typedef __attribute__((ext_vector_type(8))) short bf16x8;
typedef __attribute__((ext_vector_type(4))) short bf16x4;
typedef __attribute__((ext_vector_type(4))) float f32x4;
typedef float f32x4u __attribute__((ext_vector_type(4), aligned(4)));  // 4B-aligned rows

static __device__ __forceinline__ short f2bf(float f) {
  __hip_bfloat16 h = __float2bfloat16(f);
  return *reinterpret_cast<short*>(&h);
}

// Build a bf16 B-fragment (8 contiguous k for one output col) from f32.
static __device__ __forceinline__ bf16x8 pack8(float v0, float v1, float v2, float v3,
                                               float v4, float v5, float v6, float v7) {
  bf16x8 r;
  r[0] = f2bf(v0); r[1] = f2bf(v1); r[2] = f2bf(v2); r[3] = f2bf(v3);
  r[4] = f2bf(v4); r[5] = f2bf(v5); r[6] = f2bf(v6); r[7] = f2bf(v7);
  return r;
}

// ---------------------------------------------------------------------------
// Single fused kernel, 1024 threads = 16 waves, 64 samples/block, grid 256.
// Phase 1: float4 embedding gather -> LDS A tile (bf16), FM linear+cross.
// Phase 2: GEMM1 (A[64,448] x W1^T) — B loaded raw f32 from W1, converted
//          in-register to bf16 fragments; +b1, ReLU -> LDS H2 tile.
// Phase 3: GEMM2 (H2[64,256] x W2^T) — same lazy-convert B; +b2, ReLU, x Wout.
// Phase 4: + fm logit, sigmoid -> out.
// No workspace, no pre-pass kernel.
// ---------------------------------------------------------------------------
__global__ __launch_bounds__(1024, 4) void deepfm_fused(
    const int* __restrict__ Xs, const float* __restrict__ Xd,
    const float* __restrict__ linW, const float* __restrict__ fmW,
    const float* __restrict__ denseW, const float* __restrict__ denseB,
    const float* __restrict__ W1, const float* __restrict__ b1,
    const float* __restrict__ W2, const float* __restrict__ b2,
    const float* __restrict__ Wout, float* __restrict__ out) {

  __shared__ __hip_bfloat16 Ash[SPB][APAD];
  __shared__ __hip_bfloat16 H2sh[SPB][H2PAD];
  __shared__ float fmlsh[SPB];
  __shared__ float redsh[SPB][8];

  const int tid = threadIdx.x;
  const size_t blk0 = (size_t)blockIdx.x * SPB;

  // ---------------- phase 1: gather + FM ----------------
  {
    const int s   = tid >> 4;     // local sample 0..63
    const int sub = tid & 15;
    const int q   = sub & 3;      // e-quarter: dims q*4..q*4+3
    const int g   = sub >> 2;     // field group: fields g+4i
    const size_t b = blk0 + s;
    const int* xrow = Xs + b * NF;

    // prefetch indices (one dependent latency round)
    int idxs[7];
#pragma unroll
    for (int i = 0; i < 7; ++i) {
      int f = g + 4 * i;
      idxs[i] = (f < NF) ? xrow[f] : 0;
    }

    f32x4 sum = (f32x4){0.f, 0.f, 0.f, 0.f};
    f32x4 sumsq = (f32x4){0.f, 0.f, 0.f, 0.f};
    float part = 0.f;

#pragma unroll
    for (int i = 0; i < 7; ++i) {
      const int f = g + 4 * i;
      if (f < NF) {
        const float* row = fmW + ((size_t)f * VOCAB + idxs[i]) * EDIM;
        f32x4 v = *reinterpret_cast<const f32x4*>(row + q * 4);
        sum += v;
        sumsq += v * v;
        bf16x4 pk;
        pk[0] = f2bf(v[0]); pk[1] = f2bf(v[1]);
        pk[2] = f2bf(v[2]); pk[3] = f2bf(v[3]);
        *reinterpret_cast<bf16x4*>(&Ash[s][f * EDIM + q * 4]) = pk;
        if (q == (i & 3))
          part += linW[(size_t)f * VOCAB + idxs[i]];
      }
    }
    // reduce sum/sumsq over field-groups g (lanes xor 4, 8)
#pragma unroll
    for (int off = 4; off <= 8; off <<= 1) {
#pragma unroll
      for (int c = 0; c < 4; ++c) {
        sum[c] += __shfl_xor(sum[c], off);
        sumsq[c] += __shfl_xor(sumsq[c], off);
      }
    }
    if (g == 0) {                 // count each e-quarter's cross exactly once
      f32x4 c4 = sum * sum - sumsq;
      part += 0.5f * (c4[0] + c4[1] + c4[2] + c4[3]);
    }
    // dense features
    float xd = (sub < DD) ? Xd[b * DD + sub] : 0.f;
    Ash[s][416 + sub] = __float2bfloat16(xd);
    Ash[s][432 + sub] = __float2bfloat16(0.f);
    if (sub < DD) part += xd * denseW[sub];
    // reduce over the 16-lane group
#pragma unroll
    for (int off = 1; off < 16; off <<= 1)
      part += __shfl_xor(part, off);
    if (sub == 0) fmlsh[s] = part + denseB[0];
  }
  __syncthreads();

  // ---------------- phase 2: GEMM1 -> H2sh ----------------
  const int wave = tid >> 6;      // 0..15
  const int lane = tid & 63;
  const int lr = lane & 15;
  const int kg = lane >> 4;
  {
    const int n0 = wave * 16;     // 16 waves x 16 cols = 256
    const float* wrow = W1 + (size_t)(n0 + lr) * KREAL;  // this lane's output col
    f32x4 acc[4];
#pragma unroll
    for (int mt = 0; mt < 4; ++mt) acc[mt] = (f32x4){0.f, 0.f, 0.f, 0.f};

#pragma unroll
    for (int kt = 0; kt < KPAD / 32; ++kt) {
      const int kbase = kt * 32 + kg * 8;
      bf16x8 bf;
      if (kt < 13) {              // fully in-bounds: two 4B-aligned vector loads
        f32x4u wa = *reinterpret_cast<const f32x4u*>(wrow + kbase);
        f32x4u wb = *reinterpret_cast<const f32x4u*>(wrow + kbase + 4);
        bf = pack8(wa[0], wa[1], wa[2], wa[3], wb[0], wb[1], wb[2], wb[3]);
      } else {                    // tail: k in [416,448), guard >= 429
        float t[8];
#pragma unroll
        for (int j = 0; j < 8; ++j) {
          int k = kbase + j;
          t[j] = (k < KREAL) ? wrow[k] : 0.f;
        }
        bf = pack8(t[0], t[1], t[2], t[3], t[4], t[5], t[6], t[7]);
      }
#pragma unroll
      for (int mt = 0; mt < 4; ++mt) {
        bf16x8 af = *reinterpret_cast<const bf16x8*>(&Ash[mt * 16 + lr][kbase]);
        acc[mt] = __builtin_amdgcn_mfma_f32_16x16x32_bf16(af, bf, acc[mt], 0, 0, 0);
      }
    }
    const int col = n0 + lr;
    const float bias = b1[col];
#pragma unroll
    for (int mt = 0; mt < 4; ++mt) {
#pragma unroll
      for (int r = 0; r < 4; ++r) {
        float v = acc[mt][r] + bias;
        v = v > 0.f ? v : 0.f;
        H2sh[mt * 16 + kg * 4 + r][col] = __float2bfloat16(v);
      }
    }
  }
  __syncthreads();

  // ---------------- phase 3: GEMM2 + Wout dot ----------------
  {
    const int c  = wave & 7;      // col-slice (16 cols)
    const int h  = wave >> 3;     // m-half (32 rows)
    const int n0 = c * 16;
    const float* wrow = W2 + (size_t)(n0 + lr) * N1;   // 1KB stride, 16B aligned
    f32x4 acc[2];
    acc[0] = (f32x4){0.f, 0.f, 0.f, 0.f};
    acc[1] = (f32x4){0.f, 0.f, 0.f, 0.f};

#pragma unroll
    for (int kt = 0; kt < N1 / 32; ++kt) {
      const int kbase = kt * 32 + kg * 8;
      f32x4 wa = *reinterpret_cast<const f32x4*>(wrow + kbase);
      f32x4 wb = *reinterpret_cast<const f32x4*>(wrow + kbase + 4);
      bf16x8 bf = pack8(wa[0], wa[1], wa[2], wa[3], wb[0], wb[1], wb[2], wb[3]);
#pragma unroll
      for (int mt = 0; mt < 2; ++mt) {
        bf16x8 af = *reinterpret_cast<const bf16x8*>(&H2sh[h * 32 + mt * 16 + lr][kbase]);
        acc[mt] = __builtin_amdgcn_mfma_f32_16x16x32_bf16(af, bf, acc[mt], 0, 0, 0);
      }
    }
    const float w0 = Wout[n0 + lr];
    const float bb0 = b2[n0 + lr];
#pragma unroll
    for (int mt = 0; mt < 2; ++mt) {
#pragma unroll
      for (int r = 0; r < 4; ++r) {
        float v = acc[mt][r] + bb0;
        v = v > 0.f ? v : 0.f;
        v *= w0;
#pragma unroll
        for (int off = 1; off < 16; off <<= 1)
          v += __shfl_xor(v, off);
        if (lr == 0) redsh[h * 32 + mt * 16 + kg * 4 + r][c] = v;
      }
    }
  }
  __syncthreads();

  // ---------------- phase 4: combine + sigmoid ----------------
  if (tid < SPB) {
    const int row = tid;
    float t = 0.f;
#pragma unroll
    for (int w = 0; w < 8; ++w) t += redsh[row][w];
    float x = fmlsh[row] + t;
    out[blk0 + row] = 1.f / (1.f + expf(-x));
  }
}

// ---------------------------------------------------------------------------
extern "C" void kernel_launch(void* const* d_in, const int* in_sizes, int n_in,
                              void* d_out, int out_size, void* d_ws, size_t ws_size,
                              hipStream_t stream) {
  const int*   Xs   = (const int*)d_in[0];
  const float* Xd   = (const float*)d_in[1];
  const float* linW = (const float*)d_in[2];
  const float* fmW  = (const float*)d_in[3];
  const float* dW   = (const float*)d_in[4];
  const float* dB   = (const float*)d_in[5];
  const float* W1   = (const float*)d_in[6];
  const float* b1   = (const float*)d_in[7];
  const float* W2   = (const float*)d_in[8];
  const float* b2   = (const float*)d_in[9];
  const float* Wout = (const float*)d_in[10];
  float* out = (float*)d_out;

  (void)d_ws; (void)ws_size;
  deepfm_fused<<<BTOT / SPB, 1024, 0, stream>>>(
      Xs, Xd, linW, fmW, dW, dB, W1, b1, W2, b2, Wout, out);
}

// Round 6
// 34.357 us; speedup vs baseline: 1.1834x; 1.1834x over previous
//
#include <hip/hip_runtime.h>
#include <hip/hip_bf16.h>
#include <math.h>

// Problem constants (DeepFM)
#define BTOT   16384
#define NF     26
#define VOCAB  100000
#define EDIM   16
#define DD     13
#define KPAD   448      // 429 padded to 14*32
#define KREAL  429
#define N1     256
#define N2     128
#define SPB    32       // samples per block
#define APAD   456      // A tile row stride (448+8)
#define H2PAD  264      // H2 tile row stride (256+8)

typedef __attribute__((ext_vector_type(8))) short bf16x8;
typedef __attribute__((ext_vector_type(4))) short bf16x4;
typedef __attribute__((ext_vector_type(4))) float f32x4;

static __device__ __forceinline__ bf16x8 ldb8(const __hip_bfloat16* p) {
  return *reinterpret_cast<const bf16x8*>(p);
}
static __device__ __forceinline__ short f2bf(float f) {
  __hip_bfloat16 h = __float2bfloat16(f);
  return *reinterpret_cast<short*>(&h);
}

// ---------------------------------------------------------------------------
// Kernel 1: repack weights -> bf16 B-fragment layout, coalesced reads.
//   W1  [256][429] f32 -> W1f[((k>>3)*256 + n)*8 + (k&7)]  (k padded to 448)
//   W2  [128][256] f32 -> W2f[((k>>3)*128 + n)*8 + (k&7)]
// ---------------------------------------------------------------------------
__global__ __launch_bounds__(512) void convert_weights(
    const float* __restrict__ W1, const float* __restrict__ W2,
    __hip_bfloat16* __restrict__ W1f, __hip_bfloat16* __restrict__ W2f) {
  const int bid = blockIdx.x;
  const int k = threadIdx.x;
  if (bid < 256) {
    const int n = bid;
    if (k < 448) {
      float v = (k < KREAL) ? W1[(size_t)n * KREAL + k] : 0.f;
      W1f[(((size_t)(k >> 3)) * N1 + n) * 8 + (k & 7)] = __float2bfloat16(v);
    }
  } else {
    const int n = bid - 256;
    if (k < 256) {
      float v = W2[(size_t)n * 256 + k];
      W2f[(((size_t)(k >> 3)) * N2 + n) * 8 + (k & 7)] = __float2bfloat16(v);
    }
  }
}

// ---------------------------------------------------------------------------
// Fused kernel: 1024 threads = 16 waves, 32 samples/block, grid 512
// (2 blocks/CU); __launch_bounds__(1024, 8) caps VGPR at 64 -> 32 waves/CU.
// Phase 1: 32 threads/sample: sub=tid&31, q=sub&3 (e-quarter), g=sub>>2
//   (field-group 0..7): thread loads fields g+8i (i=0..3), quarter q,
//   exactly one lin gather per thread. -> LDS A tile (bf16) + FM logit.
// Phase 2: GEMM1 (A[32,448] x W1f^T): wave = 16 cols, 2 m-tiles. +b1,ReLU.
// Phase 3: GEMM2 (H2[32,256] x W2f^T): wave = (col-slice c=w&7, m-half
//   h=w>>3). +b2, ReLU, x Wout, 16-lane reduce.
// Phase 4: + fm logit, sigmoid -> out.
// ---------------------------------------------------------------------------
__global__ __launch_bounds__(1024, 8) void deepfm_fused(
    const int* __restrict__ Xs, const float* __restrict__ Xd,
    const float* __restrict__ linW, const float* __restrict__ fmW,
    const float* __restrict__ denseW, const float* __restrict__ denseB,
    const __hip_bfloat16* __restrict__ W1f, const float* __restrict__ b1,
    const __hip_bfloat16* __restrict__ W2f, const float* __restrict__ b2,
    const float* __restrict__ Wout, float* __restrict__ out) {

  __shared__ __hip_bfloat16 Ash[SPB][APAD];
  __shared__ __hip_bfloat16 H2sh[SPB][H2PAD];
  __shared__ float fmlsh[SPB];
  __shared__ float redsh[SPB][8];

  const int tid = threadIdx.x;
  const size_t blk0 = (size_t)blockIdx.x * SPB;

  // ---------------- phase 1: gather + FM ----------------
  {
    const int s   = tid >> 5;     // local sample 0..31
    const int sub = tid & 31;
    const int q   = sub & 3;      // e-quarter: dims q*4..q*4+3
    const int g   = sub >> 2;     // field group 0..7: fields g+8i
    const size_t b = blk0 + s;
    const int* xrow = Xs + b * NF;

    // prefetch indices (one dependent latency round); i=3 valid only g<2
    int idxs[4];
#pragma unroll
    for (int i = 0; i < 4; ++i) {
      int f = g + 8 * i;
      idxs[i] = (f < NF) ? xrow[f] : 0;
    }

    f32x4 sum = (f32x4){0.f, 0.f, 0.f, 0.f};
    f32x4 sumsq = (f32x4){0.f, 0.f, 0.f, 0.f};
    float part = 0.f;

#pragma unroll
    for (int i = 0; i < 4; ++i) {
      const int f = g + 8 * i;
      if (f < NF) {
        const float* row = fmW + ((size_t)f * VOCAB + idxs[i]) * EDIM;
        f32x4 v = *reinterpret_cast<const f32x4*>(row + q * 4);
        sum += v;
        sumsq += v * v;
        bf16x4 pk;
        pk[0] = f2bf(v[0]); pk[1] = f2bf(v[1]);
        pk[2] = f2bf(v[2]); pk[3] = f2bf(v[3]);
        *reinterpret_cast<bf16x4*>(&Ash[s][f * EDIM + q * 4]) = pk;
        if (q == (i & 3))            // exactly one lin gather per thread
          part += linW[(size_t)f * VOCAB + idxs[i]];
      }
    }
    // reduce sum/sumsq over the 8 field-groups (lanes xor 4, 8, 16)
#pragma unroll
    for (int off = 4; off <= 16; off <<= 1) {
#pragma unroll
      for (int c = 0; c < 4; ++c) {
        sum[c] += __shfl_xor(sum[c], off);
        sumsq[c] += __shfl_xor(sumsq[c], off);
      }
    }
    if (g == 0) {                 // count each e-quarter's cross exactly once
      f32x4 c4 = sum * sum - sumsq;
      part += 0.5f * (c4[0] + c4[1] + c4[2] + c4[3]);
    }
    // dense features: sub 0..31 covers A cols 416..447 in one write
    float xd = (sub < DD) ? Xd[b * DD + sub] : 0.f;
    Ash[s][416 + sub] = __float2bfloat16(xd);
    if (sub < DD) part += xd * denseW[sub];
    // reduce over the 32-lane sample group
#pragma unroll
    for (int off = 1; off < 32; off <<= 1)
      part += __shfl_xor(part, off);
    if (sub == 0) fmlsh[s] = part + denseB[0];
  }
  __syncthreads();

  // ---------------- phase 2: GEMM1 -> H2sh ----------------
  const int wave = tid >> 6;      // 0..15
  const int lane = tid & 63;
  const int lr = lane & 15;
  const int kg = lane >> 4;
  {
    const int n0 = wave * 16;     // 16 waves x 16 cols = 256
    f32x4 acc[2];
    acc[0] = (f32x4){0.f, 0.f, 0.f, 0.f};
    acc[1] = (f32x4){0.f, 0.f, 0.f, 0.f};

#pragma unroll
    for (int kt = 0; kt < KPAD / 32; ++kt) {
      const int kbase = kt * 32 + kg * 8;
      bf16x8 bf = ldb8(W1f + ((size_t)(kbase >> 3) * N1 + n0 + lr) * 8);
#pragma unroll
      for (int mt = 0; mt < 2; ++mt) {
        bf16x8 af = *reinterpret_cast<const bf16x8*>(&Ash[mt * 16 + lr][kbase]);
        acc[mt] = __builtin_amdgcn_mfma_f32_16x16x32_bf16(af, bf, acc[mt], 0, 0, 0);
      }
    }
    const int col = n0 + lr;
    const float bias = b1[col];
#pragma unroll
    for (int mt = 0; mt < 2; ++mt) {
#pragma unroll
      for (int r = 0; r < 4; ++r) {
        float v = acc[mt][r] + bias;
        v = v > 0.f ? v : 0.f;
        H2sh[mt * 16 + kg * 4 + r][col] = __float2bfloat16(v);
      }
    }
  }
  __syncthreads();

  // ---------------- phase 3: GEMM2 + Wout dot ----------------
  {
    const int c  = wave & 7;      // col-slice (16 cols)
    const int h  = wave >> 3;     // m-half (16 rows)
    const int n0 = c * 16;
    f32x4 acc = (f32x4){0.f, 0.f, 0.f, 0.f};

#pragma unroll
    for (int kt = 0; kt < N1 / 32; ++kt) {
      const int kbase = kt * 32 + kg * 8;
      bf16x8 bf = ldb8(W2f + ((size_t)(kbase >> 3) * N2 + n0 + lr) * 8);
      bf16x8 af = *reinterpret_cast<const bf16x8*>(&H2sh[h * 16 + lr][kbase]);
      acc = __builtin_amdgcn_mfma_f32_16x16x32_bf16(af, bf, acc, 0, 0, 0);
    }
    const float w0 = Wout[n0 + lr];
    const float bb0 = b2[n0 + lr];
#pragma unroll
    for (int r = 0; r < 4; ++r) {
      float v = acc[r] + bb0;
      v = v > 0.f ? v : 0.f;
      v *= w0;
#pragma unroll
      for (int off = 1; off < 16; off <<= 1)
        v += __shfl_xor(v, off);
      if (lr == 0) redsh[h * 16 + kg * 4 + r][c] = v;
    }
  }
  __syncthreads();

  // ---------------- phase 4: combine + sigmoid ----------------
  if (tid < SPB) {
    const int row = tid;
    float t = 0.f;
#pragma unroll
    for (int w = 0; w < 8; ++w) t += redsh[row][w];
    float x = fmlsh[row] + t;
    out[blk0 + row] = 1.f / (1.f + expf(-x));
  }
}

// ---------------------------------------------------------------------------
extern "C" void kernel_launch(void* const* d_in, const int* in_sizes, int n_in,
                              void* d_out, int out_size, void* d_ws, size_t ws_size,
                              hipStream_t stream) {
  const int*   Xs   = (const int*)d_in[0];
  const float* Xd   = (const float*)d_in[1];
  const float* linW = (const float*)d_in[2];
  const float* fmW  = (const float*)d_in[3];
  const float* dW   = (const float*)d_in[4];
  const float* dB   = (const float*)d_in[5];
  const float* W1   = (const float*)d_in[6];
  const float* b1   = (const float*)d_in[7];
  const float* W2   = (const float*)d_in[8];
  const float* b2   = (const float*)d_in[9];
  const float* Wout = (const float*)d_in[10];
  float* out = (float*)d_out;

  char* ws = (char*)d_ws;
  __hip_bfloat16* W1f = (__hip_bfloat16*)(ws);             // 448*256*2 = 229,376
  __hip_bfloat16* W2f = (__hip_bfloat16*)(ws + 229376);    // 256*128*2 =  65,536

  convert_weights<<<384, 512, 0, stream>>>(W1, W2, W1f, W2f);
  deepfm_fused<<<BTOT / SPB, 1024, 0, stream>>>(
      Xs, Xd, linW, fmW, dW, dB, W1f, b1, W2f, b2, Wout, out);
}